// Round 2
// baseline (312.338 us; speedup 1.0000x reference)
//
#include <hip/hip_runtime.h>
#include <hip/hip_bf16.h>

// PopulationODE: explicit Euler, L=512 steps, B=32768 trajectories, 4 states.
// Output [L,4,B] fp32 = 256 MiB -> write-bandwidth-bound.
//
// R1 lesson: single-pass (one thread/trajectory, 512 waves total = 2 waves/CU)
// is latency-bound at ~1 TB/s (measured 272 us) while fillBuffer hits 6.5 TB/s
// on the same buffer. Fix: checkpoint (phase 1, 512 waves, no output stream)
// + replay (phase 2, 16384 waves, pure coalesced write stream).

#define ODE_L 512
#define ODE_B 32768
#define CKPT_STRIDE 16                    // steps per checkpoint chunk
#define N_CKPT (ODE_L / CKPT_STRIDE)      // 32 checkpoints
#define CKPT_BYTES ((size_t)N_CKPT * 4 * ODE_B * sizeof(float))  // 16 MiB

#define LOAD_W() \
    const float w0  = w[0],  w1  = w[1],  w2  = w[2]; \
    const float w3  = w[3],  w4  = w[4],  w5  = w[5],  w6  = w[6],  w7  = w[7],  w8  = w[8]; \
    const float w9  = w[9],  w10 = w[10], w11 = w[11], w12 = w[12], w13 = w[13], w14 = w[14]; \
    const float w15 = w[15], w16 = w[16], w17 = w[17], w18 = w[18], w19 = w[19], w20 = w[20]

#define EULER_STEP(h) do { \
    const float dA = w0  + w1  * A + w2  * A * A; \
    const float dT = w3  + w4  * T + w5  * T * T + w6  * A + w7  * A * A + w8  * A * T; \
    const float dN = w9  + w10 * N + w11 * N * N + w12 * T + w13 * T * T + w14 * T * N; \
    const float dC = w15 + w16 * C + w17 * C * C + w18 * N + w19 * N * N + w20 * N * C; \
    A = A + (h) * dA; \
    T = T + (h) * dT; \
    N = N + (h) * dN; \
    C = C + (h) * dC; \
} while (0)

// ---------------- Phase 1: serial integrate, store checkpoints only ---------
__global__ __launch_bounds__(64) void ode_phase1(
    const float* __restrict__ s_grid,   // [L]
    const float* __restrict__ y0,       // [4, B]
    const float* __restrict__ w,        // [21]
    float* __restrict__ ckpt)           // [N_CKPT, 4, B]
{
    __shared__ float sh_h[ODE_L];       // h[j] = s[j+1]-s[j], h[511]=0 pad

    const int tid = threadIdx.x;
    for (int i = tid; i < ODE_L; i += 64) {
        const float s0 = s_grid[i];
        const float s1 = (i < ODE_L - 1) ? s_grid[i + 1] : s0;
        sh_h[i] = s1 - s0;
    }

    LOAD_W();
    __syncthreads();

    const int b = blockIdx.x * 64 + tid;
    float A = y0[0 * ODE_B + b];
    float T = y0[1 * ODE_B + b];
    float N = y0[2 * ODE_B + b];
    float C = y0[3 * ODE_B + b];

    for (int c = 0; c < N_CKPT; ++c) {
        // state entering chunk c == y_{16c} -> checkpoint c
        const size_t cb = (size_t)c * (4 * ODE_B) + (size_t)b;
        ckpt[cb + 0 * ODE_B] = A;
        ckpt[cb + 1 * ODE_B] = T;
        ckpt[cb + 2 * ODE_B] = N;
        ckpt[cb + 3 * ODE_B] = C;

        const int j0 = c * CKPT_STRIDE;
        #pragma unroll
        for (int u = 0; u < CKPT_STRIDE / 4; ++u) {
            // batch 4 h-values per LDS read to keep ds latency off the chain
            const float4 h4 = *(const float4*)&sh_h[j0 + 4 * u];
            EULER_STEP(h4.x);
            EULER_STEP(h4.y);
            EULER_STEP(h4.z);
            EULER_STEP(h4.w);
        }
        // last chunk's final step uses h[511]=0 (harmless dummy)
    }
}

// ---------------- Phase 2: replay 15 steps/chunk, stream all rows -----------
__global__ __launch_bounds__(256) void ode_phase2(
    const float* __restrict__ s_grid,   // [L]
    const float* __restrict__ w,        // [21]
    const float* __restrict__ ckpt,     // [N_CKPT, 4, B]
    float* __restrict__ out)            // [L, 4, B]
{
    __shared__ float sh_s[CKPT_STRIDE]; // s[i0 .. i0+15]

    const int c  = blockIdx.x;          // chunk 0..31
    const int i0 = c * CKPT_STRIDE;
    const int tid = threadIdx.x;
    if (tid < CKPT_STRIDE) sh_s[tid] = s_grid[i0 + tid];

    LOAD_W();
    __syncthreads();

    const int b = blockIdx.y * 256 + tid;

    const size_t cb = (size_t)c * (4 * ODE_B) + (size_t)b;
    float A = ckpt[cb + 0 * ODE_B];
    float T = ckpt[cb + 1 * ODE_B];
    float N = ckpt[cb + 2 * ODE_B];
    float C = ckpt[cb + 3 * ODE_B];

    // row i0 = checkpoint state itself
    size_t ob = (size_t)i0 * (4 * ODE_B) + (size_t)b;
    out[ob + 0 * ODE_B] = A;
    out[ob + 1 * ODE_B] = T;
    out[ob + 2 * ODE_B] = N;
    out[ob + 3 * ODE_B] = C;

    #pragma unroll
    for (int u = 0; u < CKPT_STRIDE - 1; ++u) {
        const float h = sh_s[u + 1] - sh_s[u];   // h[i0+u]
        EULER_STEP(h);
        const size_t o = ob + (size_t)(u + 1) * (4 * ODE_B);
        out[o + 0 * ODE_B] = A;
        out[o + 1 * ODE_B] = T;
        out[o + 2 * ODE_B] = N;
        out[o + 3 * ODE_B] = C;
    }
}

// ---------------- Fallback: R1 single-pass kernel (if ws too small) ---------
__global__ __launch_bounds__(64) void ode_single(
    const float* __restrict__ s_grid, const float* __restrict__ y0,
    const float* __restrict__ w, float* __restrict__ out)
{
    __shared__ float sh_s[ODE_L];
    const int tid = threadIdx.x;
    for (int i = tid; i < ODE_L; i += 64) sh_s[i] = s_grid[i];
    LOAD_W();
    __syncthreads();

    const int b = blockIdx.x * 64 + tid;
    float A = y0[0 * ODE_B + b], T = y0[1 * ODE_B + b];
    float N = y0[2 * ODE_B + b], C = y0[3 * ODE_B + b];
    out[0 * ODE_B + b] = A; out[1 * ODE_B + b] = T;
    out[2 * ODE_B + b] = N; out[3 * ODE_B + b] = C;
    float s_prev = sh_s[0];
    for (int i = 1; i < ODE_L; ++i) {
        const float s_cur = sh_s[i];
        const float h = s_cur - s_prev;
        s_prev = s_cur;
        EULER_STEP(h);
        const size_t base = (size_t)i * (4 * ODE_B) + (size_t)b;
        out[base + 0 * ODE_B] = A; out[base + 1 * ODE_B] = T;
        out[base + 2 * ODE_B] = N; out[base + 3 * ODE_B] = C;
    }
}

extern "C" void kernel_launch(void* const* d_in, const int* in_sizes, int n_in,
                              void* d_out, int out_size, void* d_ws, size_t ws_size,
                              hipStream_t stream) {
    (void)in_sizes; (void)n_in; (void)out_size;

    const float* s_grid = (const float*)d_in[0];
    const float* y0     = (const float*)d_in[1];
    const float* w      = (const float*)d_in[2];
    float* out          = (float*)d_out;

    if (ws_size >= CKPT_BYTES) {
        float* ckpt = (float*)d_ws;
        // Phase 1: 512 blocks x 64 threads, one thread per trajectory.
        ode_phase1<<<dim3(ODE_B / 64), dim3(64), 0, stream>>>(s_grid, y0, w, ckpt);
        // Phase 2: 32 chunks x 128 b-blocks x 256 threads = 16384 waves.
        ode_phase2<<<dim3(N_CKPT, ODE_B / 256), dim3(256), 0, stream>>>(s_grid, w, ckpt, out);
    } else {
        ode_single<<<dim3(ODE_B / 64), dim3(64), 0, stream>>>(s_grid, y0, w, out);
    }
}